// Round 1
// baseline (130.117 us; speedup 1.0000x reference)
//
#include <hip/hip_runtime.h>

// Problem constants (from reference): B=32, T=1024, D=1024, N_ITER=256, SR=4
#define BB 32
#define TT 1024
#define DD 1024
#define NIT 256
#define SRR 4

// ---------------------------------------------------------------------------
// Kernel 1: per-(b,t) sequential Euler integration of the warp function.
// Fast path: f stays in [t, t+0.25] for the bench data, so the two velocity
// rows needed are ds[b, r0, :] and ds[b, r0+1, :] (contiguous 1KB each),
// prefetched as float4 chunks. A predicated gather fallback keeps general
// correctness if floor(f) ever leaves r0.
// ---------------------------------------------------------------------------
__global__ __launch_bounds__(256) void gw_ode_kernel(const float* __restrict__ ds,
                                                     float* __restrict__ f_out) {
    const int gid = blockIdx.x * blockDim.x + threadIdx.x;   // b*T + t
    if (gid >= BB * TT) return;
    const int b = gid >> 10;
    const int t = gid & (TT - 1);
    const float inv = 1.0f / (float)(NIT * SRR);             // 1/1024, exact
    const int r0 = (t < TT - 2) ? t : (TT - 2);

    const float* rowA = ds + (size_t)(b * TT + r0) * NIT;    // ds[b, r0, :]
    const float* rowB = rowA + NIT;                          // ds[b, r0+1, :]
    const float4* pA = (const float4*)rowA;
    const float4* pB = (const float4*)rowB;

    // f0 = clip(t + ds[b,t,0]/1024, 0, T-1)
    float f = (float)t + ds[(size_t)gid * NIT] * inv;
    f = fminf(fmaxf(f, 0.0f), (float)(TT - 1));

    const int NC = NIT / 4;           // 64 float4 chunks per row
    float4 a0 = pA[0], b0 = pB[0];    // chunk c
    float4 a1 = pA[1], b1 = pB[1];    // chunk c+1 (prefetch depth 2)

    for (int c = 0; c < NC; ++c) {
        const int cpre = (c + 2 < NC) ? (c + 2) : (NC - 1);
        float4 a2 = pA[cpre];
        float4 b2 = pB[cpre];

        const float av[4] = {a0.x, a0.y, a0.z, a0.w};
        const float bv[4] = {b0.x, b0.y, b0.z, b0.w};
#pragma unroll
        for (int j = 0; j < 4; ++j) {
            const int i = 4 * c + j;
            if (i == 0) continue;     // step 0 consumed by f0 init
            int i0 = (int)floorf(f);
            i0 = min(max(i0, 0), TT - 2);
            float d0, d1;
            if (i0 == r0) {           // fast path (always taken for bench data)
                d0 = av[j] * inv;
                d1 = bv[j] * inv;
            } else {                  // general gather fallback
                d0 = ds[(size_t)(b * TT + i0) * NIT + i] * inv;
                d1 = ds[(size_t)(b * TT + i0 + 1) * NIT + i] * inv;
            }
            const float tfr = f - (float)i0;
            f = f + (d0 + tfr * (d1 - d0));
            f = fminf(fmaxf(f, 0.0f), (float)(TT - 1));
        }
        a0 = a1; b0 = b1;
        a1 = a2; b1 = b2;
    }
    f_out[gid] = f;
}

// ---------------------------------------------------------------------------
// Kernel 2: Catmull-Rom cubic resampling. One block per (b,t) output row;
// 256 threads x float4 = 1024 channels. Weights uniform across the row.
// ---------------------------------------------------------------------------
__global__ __launch_bounds__(256) void cubic_kernel(const float* __restrict__ xs,
                                                    const float* __restrict__ f_in,
                                                    float* __restrict__ out) {
    const int bt = blockIdx.x;            // b*T + t
    const int b = bt >> 10;

    const float fv = f_in[bt];
    int i1 = (int)floorf(fv);
    i1 = min(max(i1, 0), TT - 1);
    const float tf = fv - (float)i1;
    const float t2 = tf * tf;
    const float t3 = t2 * tf;
    const float w0 = -0.5f * t3 + t2 - 0.5f * tf;
    const float w1 = 1.5f * t3 - 2.5f * t2 + 1.0f;
    const float w2 = -1.5f * t3 + 2.0f * t2 + 0.5f * tf;
    const float w3 = 0.5f * t3 - 0.5f * t2;

    const int j0 = max(i1 - 1, 0);
    const int j2 = min(i1 + 1, TT - 1);
    const int j3 = min(i1 + 2, TT - 1);

    const size_t base = (size_t)b * TT * DD;
    const float4* r0 = (const float4*)(xs + base + (size_t)j0 * DD);
    const float4* r1 = (const float4*)(xs + base + (size_t)i1 * DD);
    const float4* r2 = (const float4*)(xs + base + (size_t)j2 * DD);
    const float4* r3 = (const float4*)(xs + base + (size_t)j3 * DD);
    float4* o = (float4*)(out + (size_t)bt * DD);

    const int d = threadIdx.x;            // 256 threads * float4 = 1024
    const float4 p0 = r0[d];
    const float4 p1 = r1[d];
    const float4 p2 = r2[d];
    const float4 p3 = r3[d];
    float4 v;
    v.x = w0 * p0.x + w1 * p1.x + w2 * p2.x + w3 * p3.x;
    v.y = w0 * p0.y + w1 * p1.y + w2 * p2.y + w3 * p3.y;
    v.z = w0 * p0.z + w1 * p1.z + w2 * p2.z + w3 * p3.z;
    v.w = w0 * p0.w + w1 * p1.w + w2 * p2.w + w3 * p3.w;
    o[d] = v;
}

extern "C" void kernel_launch(void* const* d_in, const int* in_sizes, int n_in,
                              void* d_out, int out_size, void* d_ws, size_t ws_size,
                              hipStream_t stream) {
    const float* xs = (const float*)d_in[0];   // (B, T, D) f32
    const float* ds = (const float*)d_in[1];   // (B, T, N_ITER) f32
    // d_in[2] = is_inference (unused)

    float* out_ys = (float*)d_out;                         // (B, T, D)
    float* out_f  = out_ys + (size_t)BB * TT * DD;         // (B, T)

    gw_ode_kernel<<<dim3((BB * TT) / 256), 256, 0, stream>>>(ds, out_f);
    cubic_kernel<<<dim3(BB * TT), 256, 0, stream>>>(xs, out_f, out_ys);
}